// Round 1
// baseline (723.618 us; speedup 1.0000x reference)
//
#include <hip/hip_runtime.h>
#include <hip/hip_bf16.h>

// Problem constants
#define Bb 256
#define Tt 256
#define Cc 384
#define Hh 6
#define Dd 64
#define Ww 64
#define Mm 128

typedef short short8 __attribute__((ext_vector_type(8)));
typedef float floatx4 __attribute__((ext_vector_type(4)));

static __device__ __forceinline__ unsigned short f2bf(float f) {
  union { __hip_bfloat16 h; unsigned short u; } cvt;
  cvt.h = __float2bfloat16(f);
  return cvt.u;
}

// ---------------- conversion kernels ----------------

__global__ __launch_bounds__(256) void cvt_x(const float4* __restrict__ x,
                                             ushort4* __restrict__ xb) {
  size_t i = (size_t)blockIdx.x * 256 + threadIdx.x;
  float4 v = x[i];
  ushort4 o;
  o.x = f2bf(v.x); o.y = f2bf(v.y); o.z = f2bf(v.z); o.w = f2bf(v.w);
  xb[i] = o;
}

__global__ __launch_bounds__(256) void cvt_misc(const float* __restrict__ qkv_w,
                                                const float* __restrict__ proj_w,
                                                const float* __restrict__ mem,
                                                unsigned short* __restrict__ wb,
                                                unsigned short* __restrict__ pwb,
                                                unsigned short* __restrict__ memk,
                                                unsigned short* __restrict__ memvt) {
  int i = blockIdx.x * 256 + threadIdx.x;   // 0 .. 442367
  wb[i] = f2bf(qkv_w[i]);                   // 1152*384 = 442368 exact
  if (i < 147456) pwb[i] = f2bf(proj_w[i]); // 384*384
  if (i < 49152) {                          // memory 128*384
    int m = i / Cc, c = i % Cc, h = c >> 6, d = c & 63;
    unsigned short bv = f2bf(mem[i]);
    memk[(h * Mm + m) * Dd + d] = bv;       // [H][M][D]
    memvt[(h * Dd + d) * Mm + m] = bv;      // [H][D][M]
  }
}

// ---------------- GEMM 1: qkv = x @ qkv_w^T + b, scatter to q/k/vt ----------------
// grid (512, 9), block 256. Direct-global MFMA fragments (contiguous-K on both sides).

__global__ __launch_bounds__(256) void gemm_qkv(const unsigned short* __restrict__ xb,  // [65536][384]
                                                const unsigned short* __restrict__ wb,  // [1152][384]
                                                const float* __restrict__ qkv_b,        // [1152]
                                                unsigned short* __restrict__ q,   // [B,H,T,D] (prescaled)
                                                unsigned short* __restrict__ k,   // [B,H,T,D]
                                                unsigned short* __restrict__ vt)  // [B,H,D,T]
{
  int tid = threadIdx.x;
  int w = tid >> 6, lane = tid & 63, quad = lane >> 4, l16 = lane & 15;
  int rowbase = blockIdx.x * 128 + (w >> 1) * 64;
  int colbase = blockIdx.y * 128 + (w & 1) * 64;

  floatx4 acc[4][4] = {};
  for (int ks = 0; ks < 12; ++ks) {
    int kk = ks * 32 + quad * 8;
    short8 a[4], b[4];
#pragma unroll
    for (int rt = 0; rt < 4; ++rt)
      a[rt] = *reinterpret_cast<const short8*>(xb + (size_t)(rowbase + rt * 16 + l16) * 384 + kk);
#pragma unroll
    for (int nt = 0; nt < 4; ++nt)
      b[nt] = *reinterpret_cast<const short8*>(wb + (size_t)(colbase + nt * 16 + l16) * 384 + kk);
#pragma unroll
    for (int rt = 0; rt < 4; ++rt)
#pragma unroll
      for (int nt = 0; nt < 4; ++nt)
        acc[rt][nt] = __builtin_amdgcn_mfma_f32_16x16x32_bf16(a[rt], b[nt], acc[rt][nt], 0, 0, 0);
  }

#pragma unroll
  for (int nt = 0; nt < 4; ++nt) {
    int col = colbase + nt * 16 + l16;             // 0..1151
    int which = col >= 768 ? 2 : (col >= 384 ? 1 : 0);
    int cc = col - which * 384;
    int h = cc >> 6, d = cc & 63;
    float bias = qkv_b[col];
#pragma unroll
    for (int rt = 0; rt < 4; ++rt) {
#pragma unroll
      for (int r = 0; r < 4; ++r) {
        int row = rowbase + rt * 16 + quad * 4 + r;    // = b*T + t
        int bidx = row >> 8, t = row & 255;
        float val = acc[rt][nt][r] + bias;
        size_t bh = (size_t)bidx * Hh + h;
        if (which == 0) {
          q[(bh * Tt + t) * Dd + d] = f2bf(val * 0.125f);   // fold 1/sqrt(64)
        } else if (which == 1) {
          k[(bh * Tt + t) * Dd + d] = f2bf(val);
        } else {
          vt[(bh * Dd + d) * Tt + t] = f2bf(val);
        }
      }
    }
  }
}

// ---------------- Attention ----------------
// grid (4, 6, 256) = (tq, h, b), block 256 = 4 waves; wave owns 16 query rows x 256 key cols.
#define PSTRIDE 280   // halfwords; 16B-aligned rows, benign bank aliasing

__global__ __launch_bounds__(256) void attn(const unsigned short* __restrict__ q,
                                            const unsigned short* __restrict__ k,
                                            const unsigned short* __restrict__ vt,
                                            const unsigned short* __restrict__ memk,
                                            const unsigned short* __restrict__ memvt,
                                            const float* __restrict__ gate,
                                            unsigned short* __restrict__ aout) // [B,T,384] bf16
{
  int tq = blockIdx.x, h = blockIdx.y, b = blockIdx.z;
  int t0 = tq * 64;
  int tid = threadIdx.x, w = tid >> 6, lane = tid & 63, quad = lane >> 4, l16 = lane & 15;

  size_t bh = (size_t)b * Hh + h;
  const unsigned short* qp = q + (bh * Tt + t0 + w * 16) * Dd;
  const unsigned short* kp = k + bh * Tt * Dd;
  const unsigned short* vp = vt + bh * Dd * Tt;
  const unsigned short* mkp = memk + (size_t)h * Mm * Dd;
  const unsigned short* mvp = memvt + (size_t)h * Dd * Mm;

  __shared__ __align__(16) unsigned short Plds[4][16 * PSTRIDE];
  unsigned short* pw = &Plds[w][0];

  // Q fragments (A-operand): m=l16, k=quad*8+j
  short8 qa[2];
#pragma unroll
  for (int ks = 0; ks < 2; ++ks)
    qa[ks] = *reinterpret_cast<const short8*>(qp + l16 * Dd + ks * 32 + quad * 8);

  // QK^T: 16 col-tiles of 16 (cols 0..127 memory, 128..255 window [t0-64, t0+63])
  floatx4 s[16] = {};
#pragma unroll
  for (int ct = 0; ct < 16; ++ct) {
    const unsigned short* kbase;
    int krow;
    if (ct < 8) {
      kbase = mkp; krow = ct * 16 + l16;
    } else {
      int j = t0 - 64 + (ct - 8) * 16 + l16;
      krow = j < 0 ? 0 : j;   // clamped; masked below
      kbase = kp;
    }
#pragma unroll
    for (int ks = 0; ks < 2; ++ks) {
      short8 bf = *reinterpret_cast<const short8*>(kbase + (size_t)krow * Dd + ks * 32 + quad * 8);
      s[ct] = __builtin_amdgcn_mfma_f32_16x16x32_bf16(qa[ks], bf, s[ct], 0, 0, 0);
    }
  }

  // mask the self-window tiles: valid iff 0 <= j <= i and i-j <= 64
#pragma unroll
  for (int ct = 8; ct < 16; ++ct) {
    int j = t0 - 64 + (ct - 8) * 16 + l16;
#pragma unroll
    for (int r = 0; r < 4; ++r) {
      int i = t0 + w * 16 + quad * 4 + r;
      bool valid = (j >= 0) && (j <= i) && (i - j <= 64);
      if (!valid) s[ct][r] = -1e30f;
    }
  }

  // softmax over 256 cols: rows live on 16 lanes of a quad -> intra-quad shuffles only
  float rm[4], rs[4], inv[4];
#pragma unroll
  for (int r = 0; r < 4; ++r) {
    float m = -1e30f;
#pragma unroll
    for (int ct = 0; ct < 16; ++ct) m = fmaxf(m, s[ct][r]);
    rm[r] = m;
  }
#pragma unroll
  for (int off = 1; off < 16; off <<= 1)
#pragma unroll
    for (int r = 0; r < 4; ++r) rm[r] = fmaxf(rm[r], __shfl_xor(rm[r], off, 64));
#pragma unroll
  for (int r = 0; r < 4; ++r) {
    float sum = 0.f;
#pragma unroll
    for (int ct = 0; ct < 16; ++ct) {
      float p = __expf(s[ct][r] - rm[r]);
      s[ct][r] = p;
      sum += p;
    }
    rs[r] = sum;
  }
#pragma unroll
  for (int off = 1; off < 16; off <<= 1)
#pragma unroll
    for (int r = 0; r < 4; ++r) rs[r] += __shfl_xor(rs[r], off, 64);
#pragma unroll
  for (int r = 0; r < 4; ++r) inv[r] = 1.0f / rs[r];

  // write P (bf16) to per-wave LDS in [row][col] layout (C-layout scatter)
#pragma unroll
  for (int ct = 0; ct < 16; ++ct)
#pragma unroll
    for (int r = 0; r < 4; ++r)
      pw[(quad * 4 + r) * PSTRIDE + ct * 16 + l16] = f2bf(s[ct][r]);

  // PV: out[16 x 64], K-loop over 256 cols in steps of 32
  floatx4 o[4] = {};
#pragma unroll
  for (int ks = 0; ks < 8; ++ks) {
    short8 pa = *reinterpret_cast<const short8*>(pw + l16 * PSTRIDE + ks * 32 + quad * 8);
    const unsigned short* vbase;
    int vc, vstride;
    if (ks < 4) {
      vbase = mvp; vc = ks * 32 + quad * 8; vstride = Mm;
    } else {
      vbase = vp; vstride = Tt;
      vc = t0 - 64 + (ks - 4) * 32 + quad * 8;
      if (vc < 0) vc = 0;   // P is exactly 0 there
    }
#pragma unroll
    for (int dt = 0; dt < 4; ++dt) {
      int d = dt * 16 + l16;
      short8 vb = *reinterpret_cast<const short8*>(vbase + (size_t)d * vstride + vc);
      o[dt] = __builtin_amdgcn_mfma_f32_16x16x32_bf16(pa, vb, o[dt], 0, 0, 0);
    }
  }

  // epilogue: normalize, gate, store bf16 row-major [b, t, c]
#pragma unroll
  for (int dt = 0; dt < 4; ++dt) {
    int c = h * 64 + dt * 16 + l16;
    float g = gate[c];
#pragma unroll
    for (int r = 0; r < 4; ++r) {
      int t = t0 + w * 16 + quad * 4 + r;
      float val = o[dt][r] * inv[r] * g;
      aout[((size_t)b * Tt + t) * Cc + c] = f2bf(val);
    }
  }
}

// ---------------- GEMM 2: out = aout @ proj_w^T + b, * loss_mask ----------------
// grid (512, 3), block 256.

__global__ __launch_bounds__(256) void gemm_proj(const unsigned short* __restrict__ ab,  // [65536][384]
                                                 const unsigned short* __restrict__ pwb, // [384][384]
                                                 const float* __restrict__ proj_b,
                                                 const float* __restrict__ loss_mask,    // [65536]
                                                 float* __restrict__ out)                // [65536][384]
{
  int tid = threadIdx.x;
  int w = tid >> 6, lane = tid & 63, quad = lane >> 4, l16 = lane & 15;
  int rowbase = blockIdx.x * 128 + (w >> 1) * 64;
  int colbase = blockIdx.y * 128 + (w & 1) * 64;

  floatx4 acc[4][4] = {};
  for (int ks = 0; ks < 12; ++ks) {
    int kk = ks * 32 + quad * 8;
    short8 a[4], b[4];
#pragma unroll
    for (int rt = 0; rt < 4; ++rt)
      a[rt] = *reinterpret_cast<const short8*>(ab + (size_t)(rowbase + rt * 16 + l16) * 384 + kk);
#pragma unroll
    for (int nt = 0; nt < 4; ++nt)
      b[nt] = *reinterpret_cast<const short8*>(pwb + (size_t)(colbase + nt * 16 + l16) * 384 + kk);
#pragma unroll
    for (int rt = 0; rt < 4; ++rt)
#pragma unroll
      for (int nt = 0; nt < 4; ++nt)
        acc[rt][nt] = __builtin_amdgcn_mfma_f32_16x16x32_bf16(a[rt], b[nt], acc[rt][nt], 0, 0, 0);
  }

#pragma unroll
  for (int nt = 0; nt < 4; ++nt) {
    int col = colbase + nt * 16 + l16;
    float bias = proj_b[col];
#pragma unroll
    for (int rt = 0; rt < 4; ++rt) {
#pragma unroll
      for (int r = 0; r < 4; ++r) {
        int row = rowbase + rt * 16 + quad * 4 + r;
        float val = (acc[rt][nt][r] + bias) * loss_mask[row];
        out[(size_t)row * 384 + col] = val;
      }
    }
  }
}

// ---------------- launcher ----------------

extern "C" void kernel_launch(void* const* d_in, const int* in_sizes, int n_in,
                              void* d_out, int out_size, void* d_ws, size_t ws_size,
                              hipStream_t stream) {
  const float* x = (const float*)d_in[0];
  const float* memory = (const float*)d_in[1];
  const float* loss_mask = (const float*)d_in[2];
  const float* qkv_w = (const float*)d_in[3];
  const float* qkv_b = (const float*)d_in[4];
  const float* proj_w = (const float*)d_in[5];
  const float* proj_b = (const float*)d_in[6];
  const float* gate = (const float*)d_in[7];
  float* out = (float*)d_out;

  char* ws = (char*)d_ws;
  // byte offsets (all 16B aligned). xb is reused as aout (dead after gemm_qkv).
  unsigned short* xb    = (unsigned short*)(ws + 0);            // 50,331,648 B
  unsigned short* qb    = (unsigned short*)(ws + 50331648);     // 50,331,648 B
  unsigned short* kb    = (unsigned short*)(ws + 100663296);    // 50,331,648 B
  unsigned short* vtb   = (unsigned short*)(ws + 150994944);    // 50,331,648 B
  unsigned short* wb    = (unsigned short*)(ws + 201326592);    //    884,736 B
  unsigned short* pwb   = (unsigned short*)(ws + 202211328);    //    294,912 B
  unsigned short* memk  = (unsigned short*)(ws + 202506240);    //     98,304 B
  unsigned short* memvt = (unsigned short*)(ws + 202604544);    //     98,304 B
  unsigned short* aout  = xb;

  cvt_x<<<dim3(24576), dim3(256), 0, stream>>>((const float4*)x, (ushort4*)xb);
  cvt_misc<<<dim3(1728), dim3(256), 0, stream>>>(qkv_w, proj_w, memory, wb, pwb, memk, memvt);
  gemm_qkv<<<dim3(512, 9), dim3(256), 0, stream>>>(xb, wb, qkv_b, qb, kb, vtb);
  attn<<<dim3(4, 6, 256), dim3(256), 0, stream>>>(qb, kb, vtb, memk, memvt, gate, aout);
  gemm_proj<<<dim3(512, 3), dim3(256), 0, stream>>>(aout, pwb, proj_b, loss_mask, out);
}

// Round 2
// 579.754 us; speedup vs baseline: 1.2481x; 1.2481x over previous
//
#include <hip/hip_runtime.h>
#include <hip/hip_bf16.h>

// Problem constants
#define Bb 256
#define Tt 256
#define Cc 384
#define Hh 6
#define Dd 64
#define Ww 64
#define Mm 128

typedef short short8 __attribute__((ext_vector_type(8)));
typedef float floatx4 __attribute__((ext_vector_type(4)));

static __device__ __forceinline__ unsigned short f2bf(float f) {
  union { __hip_bfloat16 h; unsigned short u; } cvt;
  cvt.h = __float2bfloat16(f);
  return cvt.u;
}

// async global->LDS, 16 bytes per lane. LDS dest is wave-uniform base + lane*16.
static __device__ __forceinline__ void gl2lds16(const unsigned short* g, unsigned short* l) {
  __builtin_amdgcn_global_load_lds(
      (const __attribute__((address_space(1))) unsigned int*)(const void*)g,
      (__attribute__((address_space(3))) unsigned int*)(void*)l,
      16, 0, 0);
}

// ---------------- conversion kernels ----------------

__global__ __launch_bounds__(256) void cvt_x(const float4* __restrict__ x,
                                             ushort4* __restrict__ xb) {
  size_t i = (size_t)blockIdx.x * 256 + threadIdx.x;
  float4 v = x[i];
  ushort4 o;
  o.x = f2bf(v.x); o.y = f2bf(v.y); o.z = f2bf(v.z); o.w = f2bf(v.w);
  xb[i] = o;
}

__global__ __launch_bounds__(256) void cvt_misc(const float* __restrict__ qkv_w,
                                                const float* __restrict__ proj_w,
                                                const float* __restrict__ mem,
                                                unsigned short* __restrict__ wb,
                                                unsigned short* __restrict__ pwb,
                                                unsigned short* __restrict__ memk,
                                                unsigned short* __restrict__ memvt) {
  int i = blockIdx.x * 256 + threadIdx.x;   // 0 .. 442367
  wb[i] = f2bf(qkv_w[i]);                   // 1152*384 = 442368 exact
  if (i < 147456) pwb[i] = f2bf(proj_w[i]); // 384*384
  if (i < 49152) {                          // memory 128*384
    int m = i / Cc, c = i % Cc, h = c >> 6, d = c & 63;
    unsigned short bv = f2bf(mem[i]);
    memk[(h * Mm + m) * Dd + d] = bv;       // [H][M][D]
    memvt[(h * Dd + d) * Mm + m] = bv;      // [H][D][M]
  }
}

// ---------------- GEMM 1: qkv = x @ qkv_w^T + b, scatter to q/k/vt ----------------
// grid (9, 512): col-tile fastest so consecutive blocks share the A row-strip (L2-hot).
// m97 structure: 128x128 tile, BK=32, global_load_lds width 16, ds_read_b128 fragments.

__global__ __launch_bounds__(256) void gemm_qkv(const unsigned short* __restrict__ xb,  // [65536][384]
                                                const unsigned short* __restrict__ wb,  // [1152][384]
                                                const float* __restrict__ qkv_b,        // [1152]
                                                unsigned short* __restrict__ q,   // [B,H,T,D] (prescaled)
                                                unsigned short* __restrict__ k,   // [B,H,T,D]
                                                unsigned short* __restrict__ vt)  // [B,H,D,T]
{
  int tid = threadIdx.x;
  int w = tid >> 6, lane = tid & 63, quad = lane >> 4, l16 = lane & 15;
  int rowbase = blockIdx.y * 128;
  int colbase = blockIdx.x * 128;
  int rowofs = (w >> 1) * 64, colofs = (w & 1) * 64;

  __shared__ __align__(16) unsigned short Alds[128 * 32];
  __shared__ __align__(16) unsigned short Blds[128 * 32];

  // staging geometry: call c (0..7) covers LDS halfwords [c*512, c*512+512),
  // i.e. rows c*16 + lane/4, k-chunk (lane%4)*8 of the row-major [128][32] tile.
  int srow = lane >> 2;            // 0..15
  int skc = (lane & 3) * 8;        // halfword k offset within BK

  floatx4 acc[4][4] = {};
  for (int ks = 0; ks < 12; ++ks) {
    int kk = ks * 32;
#pragma unroll
    for (int c = w; c < 8; c += 4) {
      gl2lds16(xb + (size_t)(rowbase + c * 16 + srow) * 384 + kk + skc,
               &Alds[c * 512 + lane * 8]);
      gl2lds16(wb + (size_t)(colbase + c * 16 + srow) * 384 + kk + skc,
               &Blds[c * 512 + lane * 8]);
    }
    __syncthreads();

    short8 a[4], b[4];
#pragma unroll
    for (int rt = 0; rt < 4; ++rt)
      a[rt] = *reinterpret_cast<const short8*>(&Alds[(rowofs + rt * 16 + l16) * 32 + quad * 8]);
#pragma unroll
    for (int nt = 0; nt < 4; ++nt)
      b[nt] = *reinterpret_cast<const short8*>(&Blds[(colofs + nt * 16 + l16) * 32 + quad * 8]);
#pragma unroll
    for (int rt = 0; rt < 4; ++rt)
#pragma unroll
      for (int nt = 0; nt < 4; ++nt)
        acc[rt][nt] = __builtin_amdgcn_mfma_f32_16x16x32_bf16(a[rt], b[nt], acc[rt][nt], 0, 0, 0);
    __syncthreads();
  }

#pragma unroll
  for (int nt = 0; nt < 4; ++nt) {
    int col = colbase + colofs + nt * 16 + l16;    // 0..1151
    int which = col >= 768 ? 2 : (col >= 384 ? 1 : 0);
    int cc = col - which * 384;
    int h = cc >> 6, d = cc & 63;
    float bias = qkv_b[col];
#pragma unroll
    for (int rt = 0; rt < 4; ++rt) {
#pragma unroll
      for (int r = 0; r < 4; ++r) {
        int row = rowbase + rowofs + rt * 16 + quad * 4 + r;   // = b*T + t
        int bidx = row >> 8, t = row & 255;
        float val = acc[rt][nt][r] + bias;
        size_t bh = (size_t)bidx * Hh + h;
        if (which == 0) {
          q[(bh * Tt + t) * Dd + d] = f2bf(val * 0.125f);   // fold 1/sqrt(64)
        } else if (which == 1) {
          k[(bh * Tt + t) * Dd + d] = f2bf(val);
        } else {
          vt[(bh * Dd + d) * Tt + t] = f2bf(val);
        }
      }
    }
  }
}

// ---------------- Attention ----------------
// grid (4, 6, 256) = (tq, h, b), block 256 = 4 waves; wave owns 16 query rows x 256 key cols.
#define PSTRIDE 280   // halfwords; 16B-aligned rows, benign bank aliasing

__global__ __launch_bounds__(256) void attn(const unsigned short* __restrict__ q,
                                            const unsigned short* __restrict__ k,
                                            const unsigned short* __restrict__ vt,
                                            const unsigned short* __restrict__ memk,
                                            const unsigned short* __restrict__ memvt,
                                            const float* __restrict__ gate,
                                            unsigned short* __restrict__ aout) // [B,T,384] bf16
{
  int tq = blockIdx.x, h = blockIdx.y, b = blockIdx.z;
  int t0 = tq * 64;
  int tid = threadIdx.x, w = tid >> 6, lane = tid & 63, quad = lane >> 4, l16 = lane & 15;

  size_t bh = (size_t)b * Hh + h;
  const unsigned short* qp = q + (bh * Tt + t0 + w * 16) * Dd;
  const unsigned short* kp = k + bh * Tt * Dd;
  const unsigned short* vp = vt + bh * Dd * Tt;
  const unsigned short* mkp = memk + (size_t)h * Mm * Dd;
  const unsigned short* mvp = memvt + (size_t)h * Dd * Mm;

  __shared__ __align__(16) unsigned short Plds[4][16 * PSTRIDE];
  unsigned short* pw = &Plds[w][0];

  // Q fragments (A-operand): m=l16, k=quad*8+j
  short8 qa[2];
#pragma unroll
  for (int ks = 0; ks < 2; ++ks)
    qa[ks] = *reinterpret_cast<const short8*>(qp + l16 * Dd + ks * 32 + quad * 8);

  // QK^T: 16 col-tiles of 16 (cols 0..127 memory, 128..255 window [t0-64, t0+63])
  floatx4 s[16] = {};
#pragma unroll
  for (int ct = 0; ct < 16; ++ct) {
    const unsigned short* kbase;
    int krow;
    if (ct < 8) {
      kbase = mkp; krow = ct * 16 + l16;
    } else {
      int j = t0 - 64 + (ct - 8) * 16 + l16;
      krow = j < 0 ? 0 : j;   // clamped; masked below
      kbase = kp;
    }
#pragma unroll
    for (int ks = 0; ks < 2; ++ks) {
      short8 bf = *reinterpret_cast<const short8*>(kbase + (size_t)krow * Dd + ks * 32 + quad * 8);
      s[ct] = __builtin_amdgcn_mfma_f32_16x16x32_bf16(qa[ks], bf, s[ct], 0, 0, 0);
    }
  }

  // mask the self-window tiles: valid iff 0 <= j <= i and i-j <= 64
#pragma unroll
  for (int ct = 8; ct < 16; ++ct) {
    int j = t0 - 64 + (ct - 8) * 16 + l16;
#pragma unroll
    for (int r = 0; r < 4; ++r) {
      int i = t0 + w * 16 + quad * 4 + r;
      bool valid = (j >= 0) && (j <= i) && (i - j <= 64);
      if (!valid) s[ct][r] = -1e30f;
    }
  }

  // softmax over 256 cols: rows live on 16 lanes of a quad -> intra-quad shuffles only
  float rm[4], rs[4], inv[4];
#pragma unroll
  for (int r = 0; r < 4; ++r) {
    float m = -1e30f;
#pragma unroll
    for (int ct = 0; ct < 16; ++ct) m = fmaxf(m, s[ct][r]);
    rm[r] = m;
  }
#pragma unroll
  for (int off = 1; off < 16; off <<= 1)
#pragma unroll
    for (int r = 0; r < 4; ++r) rm[r] = fmaxf(rm[r], __shfl_xor(rm[r], off, 64));
#pragma unroll
  for (int r = 0; r < 4; ++r) {
    float sum = 0.f;
#pragma unroll
    for (int ct = 0; ct < 16; ++ct) {
      float p = __expf(s[ct][r] - rm[r]);
      s[ct][r] = p;
      sum += p;
    }
    rs[r] = sum;
  }
#pragma unroll
  for (int off = 1; off < 16; off <<= 1)
#pragma unroll
    for (int r = 0; r < 4; ++r) rs[r] += __shfl_xor(rs[r], off, 64);
#pragma unroll
  for (int r = 0; r < 4; ++r) inv[r] = 1.0f / rs[r];

  // write P (bf16) to per-wave LDS in [row][col] layout (C-layout scatter)
#pragma unroll
  for (int ct = 0; ct < 16; ++ct)
#pragma unroll
    for (int r = 0; r < 4; ++r)
      pw[(quad * 4 + r) * PSTRIDE + ct * 16 + l16] = f2bf(s[ct][r]);

  // PV: out[16 x 64], K-loop over 256 cols in steps of 32
  floatx4 o[4] = {};
#pragma unroll
  for (int ks = 0; ks < 8; ++ks) {
    short8 pa = *reinterpret_cast<const short8*>(pw + l16 * PSTRIDE + ks * 32 + quad * 8);
    const unsigned short* vbase;
    int vc, vstride;
    if (ks < 4) {
      vbase = mvp; vc = ks * 32 + quad * 8; vstride = Mm;
    } else {
      vbase = vp; vstride = Tt;
      vc = t0 - 64 + (ks - 4) * 32 + quad * 8;
      if (vc < 0) vc = 0;   // P is exactly 0 there
    }
#pragma unroll
    for (int dt = 0; dt < 4; ++dt) {
      int d = dt * 16 + l16;
      short8 vb = *reinterpret_cast<const short8*>(vbase + (size_t)d * vstride + vc);
      o[dt] = __builtin_amdgcn_mfma_f32_16x16x32_bf16(pa, vb, o[dt], 0, 0, 0);
    }
  }

  // epilogue: normalize, gate, store bf16 row-major [b, t, c]
#pragma unroll
  for (int dt = 0; dt < 4; ++dt) {
    int c = h * 64 + dt * 16 + l16;
    float g = gate[c];
#pragma unroll
    for (int r = 0; r < 4; ++r) {
      int t = t0 + w * 16 + quad * 4 + r;
      float val = o[dt][r] * inv[r] * g;
      aout[((size_t)b * Tt + t) * Cc + c] = f2bf(val);
    }
  }
}

// ---------------- GEMM 2: out = aout @ proj_w^T + b, * loss_mask ----------------
// grid (3, 512), m97 structure, same as gemm_qkv.

__global__ __launch_bounds__(256) void gemm_proj(const unsigned short* __restrict__ ab,  // [65536][384]
                                                 const unsigned short* __restrict__ pwb, // [384][384]
                                                 const float* __restrict__ proj_b,
                                                 const float* __restrict__ loss_mask,    // [65536]
                                                 float* __restrict__ out)                // [65536][384]
{
  int tid = threadIdx.x;
  int w = tid >> 6, lane = tid & 63, quad = lane >> 4, l16 = lane & 15;
  int rowbase = blockIdx.y * 128;
  int colbase = blockIdx.x * 128;
  int rowofs = (w >> 1) * 64, colofs = (w & 1) * 64;

  __shared__ __align__(16) unsigned short Alds[128 * 32];
  __shared__ __align__(16) unsigned short Blds[128 * 32];

  int srow = lane >> 2;
  int skc = (lane & 3) * 8;

  floatx4 acc[4][4] = {};
  for (int ks = 0; ks < 12; ++ks) {
    int kk = ks * 32;
#pragma unroll
    for (int c = w; c < 8; c += 4) {
      gl2lds16(ab + (size_t)(rowbase + c * 16 + srow) * 384 + kk + skc,
               &Alds[c * 512 + lane * 8]);
      gl2lds16(pwb + (size_t)(colbase + c * 16 + srow) * 384 + kk + skc,
               &Blds[c * 512 + lane * 8]);
    }
    __syncthreads();

    short8 a[4], b[4];
#pragma unroll
    for (int rt = 0; rt < 4; ++rt)
      a[rt] = *reinterpret_cast<const short8*>(&Alds[(rowofs + rt * 16 + l16) * 32 + quad * 8]);
#pragma unroll
    for (int nt = 0; nt < 4; ++nt)
      b[nt] = *reinterpret_cast<const short8*>(&Blds[(colofs + nt * 16 + l16) * 32 + quad * 8]);
#pragma unroll
    for (int rt = 0; rt < 4; ++rt)
#pragma unroll
      for (int nt = 0; nt < 4; ++nt)
        acc[rt][nt] = __builtin_amdgcn_mfma_f32_16x16x32_bf16(a[rt], b[nt], acc[rt][nt], 0, 0, 0);
    __syncthreads();
  }

#pragma unroll
  for (int nt = 0; nt < 4; ++nt) {
    int col = colbase + colofs + nt * 16 + l16;
    float bias = proj_b[col];
#pragma unroll
    for (int rt = 0; rt < 4; ++rt) {
#pragma unroll
      for (int r = 0; r < 4; ++r) {
        int row = rowbase + rowofs + rt * 16 + quad * 4 + r;
        float val = (acc[rt][nt][r] + bias) * loss_mask[row];
        out[(size_t)row * 384 + col] = val;
      }
    }
  }
}

// ---------------- launcher ----------------

extern "C" void kernel_launch(void* const* d_in, const int* in_sizes, int n_in,
                              void* d_out, int out_size, void* d_ws, size_t ws_size,
                              hipStream_t stream) {
  const float* x = (const float*)d_in[0];
  const float* memory = (const float*)d_in[1];
  const float* loss_mask = (const float*)d_in[2];
  const float* qkv_w = (const float*)d_in[3];
  const float* qkv_b = (const float*)d_in[4];
  const float* proj_w = (const float*)d_in[5];
  const float* proj_b = (const float*)d_in[6];
  const float* gate = (const float*)d_in[7];
  float* out = (float*)d_out;

  char* ws = (char*)d_ws;
  // byte offsets (all 16B aligned). xb is reused as aout (dead after gemm_qkv).
  unsigned short* xb    = (unsigned short*)(ws + 0);            // 50,331,648 B
  unsigned short* qb    = (unsigned short*)(ws + 50331648);     // 50,331,648 B
  unsigned short* kb    = (unsigned short*)(ws + 100663296);    // 50,331,648 B
  unsigned short* vtb   = (unsigned short*)(ws + 150994944);    // 50,331,648 B
  unsigned short* wb    = (unsigned short*)(ws + 201326592);    //    884,736 B
  unsigned short* pwb   = (unsigned short*)(ws + 202211328);    //    294,912 B
  unsigned short* memk  = (unsigned short*)(ws + 202506240);    //     98,304 B
  unsigned short* memvt = (unsigned short*)(ws + 202604544);    //     98,304 B
  unsigned short* aout  = xb;

  cvt_x<<<dim3(24576), dim3(256), 0, stream>>>((const float4*)x, (ushort4*)xb);
  cvt_misc<<<dim3(1728), dim3(256), 0, stream>>>(qkv_w, proj_w, memory, wb, pwb, memk, memvt);
  gemm_qkv<<<dim3(9, 512), dim3(256), 0, stream>>>(xb, wb, qkv_b, qb, kb, vtb);
  attn<<<dim3(4, 6, 256), dim3(256), 0, stream>>>(qb, kb, vtb, memk, memvt, gate, aout);
  gemm_proj<<<dim3(3, 512), dim3(256), 0, stream>>>(aout, pwb, proj_b, loss_mask, out);
}

// Round 3
// 570.175 us; speedup vs baseline: 1.2691x; 1.0168x over previous
//
#include <hip/hip_runtime.h>
#include <hip/hip_bf16.h>

// Problem constants
#define Bb 256
#define Tt 256
#define Cc 384
#define Hh 6
#define Dd 64
#define Ww 64
#define Mm 128

typedef short short8 __attribute__((ext_vector_type(8)));
typedef float floatx4 __attribute__((ext_vector_type(4)));

static __device__ __forceinline__ unsigned short f2bf(float f) {
  union { __hip_bfloat16 h; unsigned short u; } cvt;
  cvt.h = __float2bfloat16(f);
  return cvt.u;
}

// async global->LDS, 16 bytes per lane. LDS dest is wave-uniform base + lane*16.
static __device__ __forceinline__ void gl2lds16(const unsigned short* g, unsigned short* l) {
  __builtin_amdgcn_global_load_lds(
      (const __attribute__((address_space(1))) unsigned int*)(const void*)g,
      (__attribute__((address_space(3))) unsigned int*)(void*)l,
      16, 0, 0);
}

// ---------------- conversion kernels ----------------

__global__ __launch_bounds__(256) void cvt_x(const float4* __restrict__ x,
                                             ushort4* __restrict__ xb) {
  size_t i = (size_t)blockIdx.x * 256 + threadIdx.x;
  float4 v = x[i];
  ushort4 o;
  o.x = f2bf(v.x); o.y = f2bf(v.y); o.z = f2bf(v.z); o.w = f2bf(v.w);
  xb[i] = o;
}

__global__ __launch_bounds__(256) void cvt_misc(const float* __restrict__ qkv_w,
                                                const float* __restrict__ proj_w,
                                                const float* __restrict__ mem,
                                                unsigned short* __restrict__ wb,
                                                unsigned short* __restrict__ pwb,
                                                unsigned short* __restrict__ memk,
                                                unsigned short* __restrict__ memvt) {
  int i = blockIdx.x * 256 + threadIdx.x;   // 0 .. 442367
  wb[i] = f2bf(qkv_w[i]);                   // 1152*384 = 442368 exact
  if (i < 147456) pwb[i] = f2bf(proj_w[i]); // 384*384
  if (i < 49152) {                          // memory 128*384
    int m = i / Cc, c = i % Cc, h = c >> 6, d = c & 63;
    unsigned short bv = f2bf(mem[i]);
    memk[(h * Mm + m) * Dd + d] = bv;       // [H][M][D]
    memvt[(h * Dd + d) * Mm + m] = bv;      // [H][D][M]
  }
}

// ---------------- GEMM 1: qkv = x @ qkv_w^T + b, scatter to q/k/vt ----------------
// grid (9, 512): col-tile fastest so consecutive blocks share the A row-strip (L2-hot).
// m97 structure: 128x128 tile, BK=32, global_load_lds width 16, ds_read_b128 fragments.

__global__ __launch_bounds__(256) void gemm_qkv(const unsigned short* __restrict__ xb,  // [65536][384]
                                                const unsigned short* __restrict__ wb,  // [1152][384]
                                                const float* __restrict__ qkv_b,        // [1152]
                                                unsigned short* __restrict__ q,   // [B,H,T,D] (prescaled)
                                                unsigned short* __restrict__ k,   // [B,H,T,D]
                                                unsigned short* __restrict__ vt)  // [B,H,D,T]
{
  int tid = threadIdx.x;
  int w = tid >> 6, lane = tid & 63, quad = lane >> 4, l16 = lane & 15;
  int rowbase = blockIdx.y * 128;
  int colbase = blockIdx.x * 128;
  int rowofs = (w >> 1) * 64, colofs = (w & 1) * 64;

  __shared__ __align__(16) unsigned short Alds[128 * 32];
  __shared__ __align__(16) unsigned short Blds[128 * 32];

  int srow = lane >> 2;            // 0..15
  int skc = (lane & 3) * 8;        // halfword k offset within BK

  floatx4 acc[4][4] = {};
  for (int ks = 0; ks < 12; ++ks) {
    int kk = ks * 32;
#pragma unroll
    for (int c = w; c < 8; c += 4) {
      gl2lds16(xb + (size_t)(rowbase + c * 16 + srow) * 384 + kk + skc,
               &Alds[c * 512 + lane * 8]);
      gl2lds16(wb + (size_t)(colbase + c * 16 + srow) * 384 + kk + skc,
               &Blds[c * 512 + lane * 8]);
    }
    __syncthreads();

    short8 a[4], b[4];
#pragma unroll
    for (int rt = 0; rt < 4; ++rt)
      a[rt] = *reinterpret_cast<const short8*>(&Alds[(rowofs + rt * 16 + l16) * 32 + quad * 8]);
#pragma unroll
    for (int nt = 0; nt < 4; ++nt)
      b[nt] = *reinterpret_cast<const short8*>(&Blds[(colofs + nt * 16 + l16) * 32 + quad * 8]);
#pragma unroll
    for (int rt = 0; rt < 4; ++rt)
#pragma unroll
      for (int nt = 0; nt < 4; ++nt)
        acc[rt][nt] = __builtin_amdgcn_mfma_f32_16x16x32_bf16(a[rt], b[nt], acc[rt][nt], 0, 0, 0);
    __syncthreads();
  }

#pragma unroll
  for (int nt = 0; nt < 4; ++nt) {
    int col = colbase + colofs + nt * 16 + l16;    // 0..1151
    int which = col >= 768 ? 2 : (col >= 384 ? 1 : 0);
    int cc = col - which * 384;
    int h = cc >> 6, d = cc & 63;
    float bias = qkv_b[col];
#pragma unroll
    for (int rt = 0; rt < 4; ++rt) {
#pragma unroll
      for (int r = 0; r < 4; ++r) {
        int row = rowbase + rowofs + rt * 16 + quad * 4 + r;   // = b*T + t
        int bidx = row >> 8, t = row & 255;
        float val = acc[rt][nt][r] + bias;
        size_t bh = (size_t)bidx * Hh + h;
        if (which == 0) {
          q[(bh * Tt + t) * Dd + d] = f2bf(val * 0.125f);   // fold 1/sqrt(64)
        } else if (which == 1) {
          k[(bh * Tt + t) * Dd + d] = f2bf(val);
        } else {
          vt[(bh * Dd + d) * Tt + t] = f2bf(val);
        }
      }
    }
  }
}

// ---------------- Attention ----------------
// grid (4, 6, 256) = (tq, h, b), block 256 = 4 waves; wave owns 16 query rows x 256 key cols.
// launch_bounds(256,1): unlock VGPR budget so K/V fragment batches stay in flight (MLP).
#define PSTRIDE 280   // halfwords; 16B-aligned rows, benign bank aliasing

__global__ __launch_bounds__(256, 1) void attn(const unsigned short* __restrict__ q,
                                               const unsigned short* __restrict__ k,
                                               const unsigned short* __restrict__ vt,
                                               const unsigned short* __restrict__ memk,
                                               const unsigned short* __restrict__ memvt,
                                               const float* __restrict__ gate,
                                               unsigned short* __restrict__ aout) // [B,T,384] bf16
{
  int tq = blockIdx.x, h = blockIdx.y, b = blockIdx.z;
  int t0 = tq * 64;
  int tid = threadIdx.x, w = tid >> 6, lane = tid & 63, quad = lane >> 4, l16 = lane & 15;

  size_t bh = (size_t)b * Hh + h;
  const unsigned short* qp = q + (bh * Tt + t0 + w * 16) * Dd;
  const unsigned short* kp = k + bh * Tt * Dd;
  const unsigned short* vp = vt + bh * Dd * Tt;
  const unsigned short* mkp = memk + (size_t)h * Mm * Dd;
  const unsigned short* mvp = memvt + (size_t)h * Dd * Mm;

  __shared__ __align__(16) unsigned short Plds[4][16 * PSTRIDE];
  unsigned short* pw = &Plds[w][0];

  // Q fragments (A-operand): m=l16, k=quad*8+j
  short8 qa[2];
#pragma unroll
  for (int ks = 0; ks < 2; ++ks)
    qa[ks] = *reinterpret_cast<const short8*>(qp + l16 * Dd + ks * 32 + quad * 8);

  floatx4 s[16] = {};

  // ---- QK^T, batch 1: memory cols 0..127 (8 tiles, 16 frags in flight) ----
  {
    short8 kf[8][2];
#pragma unroll
    for (int ct = 0; ct < 8; ++ct) {
      int krow = ct * 16 + l16;
#pragma unroll
      for (int ks = 0; ks < 2; ++ks)
        kf[ct][ks] = *reinterpret_cast<const short8*>(mkp + (size_t)krow * Dd + ks * 32 + quad * 8);
    }
#pragma unroll
    for (int ct = 0; ct < 8; ++ct)
#pragma unroll
      for (int ks = 0; ks < 2; ++ks)
        s[ct] = __builtin_amdgcn_mfma_f32_16x16x32_bf16(qa[ks], kf[ct][ks], s[ct], 0, 0, 0);
  }
  // ---- QK^T, batch 2: window cols [t0-64, t0+63] ----
  {
    short8 kf[8][2];
#pragma unroll
    for (int ct = 0; ct < 8; ++ct) {
      int j = t0 - 64 + ct * 16 + l16;
      int krow = j < 0 ? 0 : j;   // clamped; masked below
#pragma unroll
      for (int ks = 0; ks < 2; ++ks)
        kf[ct][ks] = *reinterpret_cast<const short8*>(kp + (size_t)krow * Dd + ks * 32 + quad * 8);
    }
#pragma unroll
    for (int ct = 0; ct < 8; ++ct)
#pragma unroll
      for (int ks = 0; ks < 2; ++ks)
        s[8 + ct] = __builtin_amdgcn_mfma_f32_16x16x32_bf16(qa[ks], kf[ct][ks], s[8 + ct], 0, 0, 0);
  }

  // ---- prefetch V batch 1 (memory part) so latency hides under softmax ----
  short8 vf[16];
#pragma unroll
  for (int ks = 0; ks < 4; ++ks)
#pragma unroll
    for (int dt = 0; dt < 4; ++dt)
      vf[ks * 4 + dt] = *reinterpret_cast<const short8*>(
          mvp + (size_t)(dt * 16 + l16) * Mm + ks * 32 + quad * 8);

  // mask the self-window tiles: valid iff 0 <= j <= i and i-j <= 64
#pragma unroll
  for (int ct = 8; ct < 16; ++ct) {
    int j = t0 - 64 + (ct - 8) * 16 + l16;
#pragma unroll
    for (int r = 0; r < 4; ++r) {
      int i = t0 + w * 16 + quad * 4 + r;
      bool valid = (j >= 0) && (j <= i) && (i - j <= 64);
      if (!valid) s[ct][r] = -1e30f;
    }
  }

  // softmax over 256 cols: rows live on 16 lanes of a quad -> intra-quad shuffles only
  float rm[4], rs[4], inv[4];
#pragma unroll
  for (int r = 0; r < 4; ++r) {
    float m = -1e30f;
#pragma unroll
    for (int ct = 0; ct < 16; ++ct) m = fmaxf(m, s[ct][r]);
    rm[r] = m;
  }
#pragma unroll
  for (int off = 1; off < 16; off <<= 1)
#pragma unroll
    for (int r = 0; r < 4; ++r) rm[r] = fmaxf(rm[r], __shfl_xor(rm[r], off, 64));
#pragma unroll
  for (int r = 0; r < 4; ++r) {
    float sum = 0.f;
#pragma unroll
    for (int ct = 0; ct < 16; ++ct) {
      float p = __expf(s[ct][r] - rm[r]);
      s[ct][r] = p;
      sum += p;
    }
    rs[r] = sum;
  }
#pragma unroll
  for (int off = 1; off < 16; off <<= 1)
#pragma unroll
    for (int r = 0; r < 4; ++r) rs[r] += __shfl_xor(rs[r], off, 64);
#pragma unroll
  for (int r = 0; r < 4; ++r) inv[r] = 1.0f / rs[r];

  // write P (bf16) to per-wave LDS in [row][col] layout (C-layout scatter)
#pragma unroll
  for (int ct = 0; ct < 16; ++ct)
#pragma unroll
    for (int r = 0; r < 4; ++r)
      pw[(quad * 4 + r) * PSTRIDE + ct * 16 + l16] = f2bf(s[ct][r]);

  // ---- PV, batch 1: memory cols (vf already in flight) ----
  floatx4 o[4] = {};
#pragma unroll
  for (int ks = 0; ks < 4; ++ks) {
    short8 pa = *reinterpret_cast<const short8*>(pw + l16 * PSTRIDE + ks * 32 + quad * 8);
#pragma unroll
    for (int dt = 0; dt < 4; ++dt)
      o[dt] = __builtin_amdgcn_mfma_f32_16x16x32_bf16(pa, vf[ks * 4 + dt], o[dt], 0, 0, 0);
  }
  // ---- PV, batch 2: window cols ----
#pragma unroll
  for (int ks = 0; ks < 4; ++ks) {
    int vc = t0 - 64 + ks * 32 + quad * 8;
    if (vc < 0) vc = 0;   // P is exactly 0 there
#pragma unroll
    for (int dt = 0; dt < 4; ++dt)
      vf[ks * 4 + dt] = *reinterpret_cast<const short8*>(
          vp + (size_t)(dt * 16 + l16) * Tt + vc);
  }
#pragma unroll
  for (int ks = 0; ks < 4; ++ks) {
    short8 pa = *reinterpret_cast<const short8*>(pw + l16 * PSTRIDE + (4 + ks) * 32 + quad * 8);
#pragma unroll
    for (int dt = 0; dt < 4; ++dt)
      o[dt] = __builtin_amdgcn_mfma_f32_16x16x32_bf16(pa, vf[ks * 4 + dt], o[dt], 0, 0, 0);
  }

  // epilogue: normalize, gate, store bf16 row-major [b, t, c]
#pragma unroll
  for (int dt = 0; dt < 4; ++dt) {
    int c = h * 64 + dt * 16 + l16;
    float g = gate[c];
#pragma unroll
    for (int r = 0; r < 4; ++r) {
      int t = t0 + w * 16 + quad * 4 + r;
      float val = o[dt][r] * inv[r] * g;
      aout[((size_t)b * Tt + t) * Cc + c] = f2bf(val);
    }
  }
}

// ---------------- GEMM 2: out = aout @ proj_w^T + b, * loss_mask ----------------
// grid (3, 512), m97 structure, same as gemm_qkv.

__global__ __launch_bounds__(256) void gemm_proj(const unsigned short* __restrict__ ab,  // [65536][384]
                                                 const unsigned short* __restrict__ pwb, // [384][384]
                                                 const float* __restrict__ proj_b,
                                                 const float* __restrict__ loss_mask,    // [65536]
                                                 float* __restrict__ out)                // [65536][384]
{
  int tid = threadIdx.x;
  int w = tid >> 6, lane = tid & 63, quad = lane >> 4, l16 = lane & 15;
  int rowbase = blockIdx.y * 128;
  int colbase = blockIdx.x * 128;
  int rowofs = (w >> 1) * 64, colofs = (w & 1) * 64;

  __shared__ __align__(16) unsigned short Alds[128 * 32];
  __shared__ __align__(16) unsigned short Blds[128 * 32];

  int srow = lane >> 2;
  int skc = (lane & 3) * 8;

  floatx4 acc[4][4] = {};
  for (int ks = 0; ks < 12; ++ks) {
    int kk = ks * 32;
#pragma unroll
    for (int c = w; c < 8; c += 4) {
      gl2lds16(ab + (size_t)(rowbase + c * 16 + srow) * 384 + kk + skc,
               &Alds[c * 512 + lane * 8]);
      gl2lds16(pwb + (size_t)(colbase + c * 16 + srow) * 384 + kk + skc,
               &Blds[c * 512 + lane * 8]);
    }
    __syncthreads();

    short8 a[4], b[4];
#pragma unroll
    for (int rt = 0; rt < 4; ++rt)
      a[rt] = *reinterpret_cast<const short8*>(&Alds[(rowofs + rt * 16 + l16) * 32 + quad * 8]);
#pragma unroll
    for (int nt = 0; nt < 4; ++nt)
      b[nt] = *reinterpret_cast<const short8*>(&Blds[(colofs + nt * 16 + l16) * 32 + quad * 8]);
#pragma unroll
    for (int rt = 0; rt < 4; ++rt)
#pragma unroll
      for (int nt = 0; nt < 4; ++nt)
        acc[rt][nt] = __builtin_amdgcn_mfma_f32_16x16x32_bf16(a[rt], b[nt], acc[rt][nt], 0, 0, 0);
    __syncthreads();
  }

#pragma unroll
  for (int nt = 0; nt < 4; ++nt) {
    int col = colbase + colofs + nt * 16 + l16;
    float bias = proj_b[col];
#pragma unroll
    for (int rt = 0; rt < 4; ++rt) {
#pragma unroll
      for (int r = 0; r < 4; ++r) {
        int row = rowbase + rowofs + rt * 16 + quad * 4 + r;
        float val = (acc[rt][nt][r] + bias) * loss_mask[row];
        out[(size_t)row * 384 + col] = val;
      }
    }
  }
}

// ---------------- launcher ----------------

extern "C" void kernel_launch(void* const* d_in, const int* in_sizes, int n_in,
                              void* d_out, int out_size, void* d_ws, size_t ws_size,
                              hipStream_t stream) {
  const float* x = (const float*)d_in[0];
  const float* memory = (const float*)d_in[1];
  const float* loss_mask = (const float*)d_in[2];
  const float* qkv_w = (const float*)d_in[3];
  const float* qkv_b = (const float*)d_in[4];
  const float* proj_w = (const float*)d_in[5];
  const float* proj_b = (const float*)d_in[6];
  const float* gate = (const float*)d_in[7];
  float* out = (float*)d_out;

  char* ws = (char*)d_ws;
  // byte offsets (all 16B aligned). xb is reused as aout (dead after gemm_qkv).
  unsigned short* xb    = (unsigned short*)(ws + 0);            // 50,331,648 B
  unsigned short* qb    = (unsigned short*)(ws + 50331648);     // 50,331,648 B
  unsigned short* kb    = (unsigned short*)(ws + 100663296);    // 50,331,648 B
  unsigned short* vtb   = (unsigned short*)(ws + 150994944);    // 50,331,648 B
  unsigned short* wb    = (unsigned short*)(ws + 201326592);    //    884,736 B
  unsigned short* pwb   = (unsigned short*)(ws + 202211328);    //    294,912 B
  unsigned short* memk  = (unsigned short*)(ws + 202506240);    //     98,304 B
  unsigned short* memvt = (unsigned short*)(ws + 202604544);    //     98,304 B
  unsigned short* aout  = xb;

  cvt_x<<<dim3(24576), dim3(256), 0, stream>>>((const float4*)x, (ushort4*)xb);
  cvt_misc<<<dim3(1728), dim3(256), 0, stream>>>(qkv_w, proj_w, memory, wb, pwb, memk, memvt);
  gemm_qkv<<<dim3(9, 512), dim3(256), 0, stream>>>(xb, wb, qkv_b, qb, kb, vtb);
  attn<<<dim3(4, 6, 256), dim3(256), 0, stream>>>(qb, kb, vtb, memk, memvt, gate, aout);
  gemm_proj<<<dim3(3, 512), dim3(256), 0, stream>>>(aout, pwb, proj_b, loss_mask, out);
}

// Round 4
// 469.017 us; speedup vs baseline: 1.5428x; 1.2157x over previous
//
#include <hip/hip_runtime.h>
#include <hip/hip_bf16.h>

// Problem constants
#define Bb 256
#define Tt 256
#define Cc 384
#define Hh 6
#define Dd 64
#define Ww 64
#define Mm 128

typedef short short8 __attribute__((ext_vector_type(8)));
typedef float floatx4 __attribute__((ext_vector_type(4)));

static __device__ __forceinline__ unsigned short f2bf(float f) {
  union { __hip_bfloat16 h; unsigned short u; } cvt;
  cvt.h = __float2bfloat16(f);
  return cvt.u;
}

// async global->LDS, 16 bytes per lane. LDS dest is wave-uniform base + lane*16.
static __device__ __forceinline__ void gl2lds16(const unsigned short* g, unsigned short* l) {
  __builtin_amdgcn_global_load_lds(
      (const __attribute__((address_space(1))) unsigned int*)(const void*)g,
      (__attribute__((address_space(3))) unsigned int*)(void*)l,
      16, 0, 0);
}

// ---------------- conversion kernels ----------------

__global__ __launch_bounds__(256) void cvt_x(const float4* __restrict__ x,
                                             ushort4* __restrict__ xb) {
  size_t i = (size_t)blockIdx.x * 256 + threadIdx.x;
  float4 v = x[i];
  ushort4 o;
  o.x = f2bf(v.x); o.y = f2bf(v.y); o.z = f2bf(v.z); o.w = f2bf(v.w);
  xb[i] = o;
}

__global__ __launch_bounds__(256) void cvt_misc(const float* __restrict__ qkv_w,
                                                const float* __restrict__ proj_w,
                                                const float* __restrict__ mem,
                                                unsigned short* __restrict__ wb,
                                                unsigned short* __restrict__ pwb,
                                                unsigned short* __restrict__ memk,
                                                unsigned short* __restrict__ memvt) {
  int i = blockIdx.x * 256 + threadIdx.x;   // 0 .. 442367
  wb[i] = f2bf(qkv_w[i]);                   // 1152*384 = 442368 exact
  if (i < 147456) pwb[i] = f2bf(proj_w[i]); // 384*384
  if (i < 49152) {                          // memory 128*384
    int m = i / Cc, c = i % Cc, h = c >> 6, d = c & 63;
    unsigned short bv = f2bf(mem[i]);
    memk[(h * Mm + m) * Dd + d] = bv;       // [H][M][D]
    memvt[(h * Dd + d) * Mm + m] = bv;      // [H][D][M]
  }
}

// ---------------- GEMM 1: qkv = x @ qkv_w^T + b, scatter to q/k/vt ----------------
// grid (9, 512): col-tile fastest so consecutive blocks share the A row-strip (L2-hot).
// m97 structure: 128x128 tile, BK=32, global_load_lds width 16, ds_read_b128 fragments.

__global__ __launch_bounds__(256) void gemm_qkv(const unsigned short* __restrict__ xb,  // [65536][384]
                                                const unsigned short* __restrict__ wb,  // [1152][384]
                                                const float* __restrict__ qkv_b,        // [1152]
                                                unsigned short* __restrict__ q,   // [B,H,T,D] (prescaled)
                                                unsigned short* __restrict__ k,   // [B,H,T,D]
                                                unsigned short* __restrict__ vt)  // [B,H,D,T]
{
  int tid = threadIdx.x;
  int w = tid >> 6, lane = tid & 63, quad = lane >> 4, l16 = lane & 15;
  int rowbase = blockIdx.y * 128;
  int colbase = blockIdx.x * 128;
  int rowofs = (w >> 1) * 64, colofs = (w & 1) * 64;

  __shared__ __align__(16) unsigned short Alds[128 * 32];
  __shared__ __align__(16) unsigned short Blds[128 * 32];

  int srow = lane >> 2;            // 0..15
  int skc = (lane & 3) * 8;        // halfword k offset within BK

  floatx4 acc[4][4] = {};
  for (int ks = 0; ks < 12; ++ks) {
    int kk = ks * 32;
#pragma unroll
    for (int c = w; c < 8; c += 4) {
      gl2lds16(xb + (size_t)(rowbase + c * 16 + srow) * 384 + kk + skc,
               &Alds[c * 512 + lane * 8]);
      gl2lds16(wb + (size_t)(colbase + c * 16 + srow) * 384 + kk + skc,
               &Blds[c * 512 + lane * 8]);
    }
    __syncthreads();

    short8 a[4], b[4];
#pragma unroll
    for (int rt = 0; rt < 4; ++rt)
      a[rt] = *reinterpret_cast<const short8*>(&Alds[(rowofs + rt * 16 + l16) * 32 + quad * 8]);
#pragma unroll
    for (int nt = 0; nt < 4; ++nt)
      b[nt] = *reinterpret_cast<const short8*>(&Blds[(colofs + nt * 16 + l16) * 32 + quad * 8]);
#pragma unroll
    for (int rt = 0; rt < 4; ++rt)
#pragma unroll
      for (int nt = 0; nt < 4; ++nt)
        acc[rt][nt] = __builtin_amdgcn_mfma_f32_16x16x32_bf16(a[rt], b[nt], acc[rt][nt], 0, 0, 0);
    __syncthreads();
  }

#pragma unroll
  for (int nt = 0; nt < 4; ++nt) {
    int col = colbase + colofs + nt * 16 + l16;    // 0..1151
    int which = col >= 768 ? 2 : (col >= 384 ? 1 : 0);
    int cc = col - which * 384;
    int h = cc >> 6, d = cc & 63;
    float bias = qkv_b[col];
#pragma unroll
    for (int rt = 0; rt < 4; ++rt) {
#pragma unroll
      for (int r = 0; r < 4; ++r) {
        int row = rowbase + rowofs + rt * 16 + quad * 4 + r;   // = b*T + t
        int bidx = row >> 8, t = row & 255;
        float val = acc[rt][nt][r] + bias;
        size_t bh = (size_t)bidx * Hh + h;
        if (which == 0) {
          q[(bh * Tt + t) * Dd + d] = f2bf(val * 0.125f);   // fold 1/sqrt(64)
        } else if (which == 1) {
          k[(bh * Tt + t) * Dd + d] = f2bf(val);
        } else {
          vt[(bh * Dd + d) * Tt + t] = f2bf(val);
        }
      }
    }
  }
}

// ---------------- Attention (LDS-staged, swizzled) ----------------
// grid (4, 6, 256) = (tq, h, b), block 256 = 4 waves; wave owns 16 query rows x 256 key cols.
// K/V staged ONCE per block via global_load_lds (was 4x redundant per-wave global loads).
// XOR chunk swizzle (slot = chunk ^ (row&7)) gives 2-way-free ds_read_b128 banking.
// LDS map (halfwords): [0,8192) Kmem | [8192,16384) Kwin | P reuses [0,16896) after
// barrier#2 | [16896,25088) Vmem | [25088,33280) Vwin. 66560 B -> 2 blocks/CU.
#define PSTRIDE 264   // hw; 528 B rows (16B-aligned), bank step 4 -> 2-way free

__global__ __launch_bounds__(256, 2) void attn(const unsigned short* __restrict__ q,
                                               const unsigned short* __restrict__ k,
                                               const unsigned short* __restrict__ vt,
                                               const unsigned short* __restrict__ memk,
                                               const unsigned short* __restrict__ memvt,
                                               const float* __restrict__ gate,
                                               unsigned short* __restrict__ aout) // [B,T,384] bf16
{
  int tq = blockIdx.x, h = blockIdx.y, b = blockIdx.z;
  int t0 = tq * 64;
  int tid = threadIdx.x, w = tid >> 6, lane = tid & 63, quad = lane >> 4, l16 = lane & 15;

  size_t bh = (size_t)b * Hh + h;
  const unsigned short* qp = q + (bh * Tt + t0 + w * 16) * Dd;
  const unsigned short* kp = k + bh * Tt * Dd;
  const unsigned short* vp = vt + bh * Dd * Tt;
  const unsigned short* mkp = memk + (size_t)h * Mm * Dd;
  const unsigned short* mvp = memvt + (size_t)h * Dd * Mm;

  __shared__ __align__(16) unsigned short lds[33280];
  unsigned short* Kmem = lds;            // [128 rows][8 chunks of 16B, swizzled]
  unsigned short* Kwin = lds + 8192;     // [128 rows][8 chunks]
  unsigned short* Pb   = lds;            // [4 waves][16 rows][PSTRIDE] after barrier#2
  unsigned short* Vmem = lds + 16896;    // [64 rows][16 chunks]
  unsigned short* Vwin = lds + 25088;    // [64 rows][16 chunks]
  unsigned short* pw = Pb + w * 16 * PSTRIDE;

  // Q fragments (A-operand): m=l16, k=quad*8+j — direct global (small, L2-hot)
  short8 qa[2];
#pragma unroll
  for (int ks = 0; ks < 2; ++ks)
    qa[ks] = *reinterpret_cast<const short8*>(qp + l16 * Dd + ks * 32 + quad * 8);

  // ---- async stage: K (mem+win) and V (mem+win), 16 DMA issues per thread ----
  // K regions: row r (128B = 8 chunks); stored chunk at slot cs holds chunk cs^(r&7).
#pragma unroll
  for (int i = 0; i < 4; ++i) {
    int G = (i * 4 + w) * 64;          // chunk group (64 chunks = 8 rows)
    int g = G + lane;
    int r = g >> 3, cs = g & 7;
    int c = cs ^ (r & 7);
    gl2lds16(mkp + r * 64 + c * 8, Kmem + G * 8 + lane * 8);
  }
#pragma unroll
  for (int i = 0; i < 4; ++i) {
    int G = (i * 4 + w) * 64;
    int g = G + lane;
    int r = g >> 3, cs = g & 7;
    int c = cs ^ (r & 7);
    int j = t0 - 64 + r;
    if (j < 0) j = 0;                  // branchless clamp; masked later
    gl2lds16(kp + (size_t)j * 64 + c * 8, Kwin + G * 8 + lane * 8);
  }
  // V regions: row d (128 cols = 16 chunks); slot cs holds chunk (cs&8)|((cs&7)^(d&7)).
#pragma unroll
  for (int i = 0; i < 4; ++i) {
    int G = (i * 4 + w) * 64;          // 64 chunks = 4 rows
    int g = G + lane;
    int d = g >> 4, cs = g & 15;
    int c = (cs & 8) | ((cs & 7) ^ (d & 7));
    gl2lds16(mvp + d * Mm + c * 8, Vmem + G * 8 + lane * 8);
  }
#pragma unroll
  for (int i = 0; i < 4; ++i) {
    int G = (i * 4 + w) * 64;
    int g = G + lane;
    int d = g >> 4, cs = g & 15;
    int c = (cs & 8) | ((cs & 7) ^ (d & 7));
    int j0 = t0 - 64 + c * 8;
    if (j0 < 0) j0 = 0;                // whole chunk below 0 -> P=0 there
    gl2lds16(vp + (size_t)d * Tt + j0, Vwin + G * 8 + lane * 8);
  }
  __syncthreads();   // drains vmcnt(0): all K/V staged

  floatx4 s[16] = {};

  // ---- QK^T memory tiles (cols 0..127): all valid ----
#pragma unroll
  for (int ct = 0; ct < 8; ++ct)
#pragma unroll
    for (int ks = 0; ks < 2; ++ks) {
      int slot = (ks * 4 + quad) ^ (l16 & 7);
      short8 bf = *reinterpret_cast<const short8*>(Kmem + (ct * 16 + l16) * 64 + slot * 8);
      s[ct] = __builtin_amdgcn_mfma_f32_16x16x32_bf16(qa[ks], bf, s[ct], 0, 0, 0);
    }
  // ---- QK^T window tiles: only ct' in [w, w+4] reachable (causal band) ----
#pragma unroll
  for (int ct = 0; ct < 8; ++ct) {
    if (ct >= w && ct <= w + 4) {
#pragma unroll
      for (int ks = 0; ks < 2; ++ks) {
        int slot = (ks * 4 + quad) ^ (l16 & 7);
        short8 bf = *reinterpret_cast<const short8*>(Kwin + (ct * 16 + l16) * 64 + slot * 8);
        s[8 + ct] = __builtin_amdgcn_mfma_f32_16x16x32_bf16(qa[ks], bf, s[8 + ct], 0, 0, 0);
      }
    }
  }
  __syncthreads();   // all waves done reading K region -> safe to overwrite with P

  // mask window tiles: valid iff 0 <= j <= i and i-j <= 64 (skipped tiles -> all -1e30)
#pragma unroll
  for (int ct = 8; ct < 16; ++ct) {
    int j = t0 - 64 + (ct - 8) * 16 + l16;
#pragma unroll
    for (int r = 0; r < 4; ++r) {
      int i = t0 + w * 16 + quad * 4 + r;
      bool valid = (j >= 0) && (j <= i) && (i - j <= 64);
      if (!valid) s[ct][r] = -1e30f;
    }
  }

  // softmax over 256 cols: rows live on 16 lanes of a quad -> intra-quad shuffles only
  float rm[4], rs[4], inv[4];
#pragma unroll
  for (int r = 0; r < 4; ++r) {
    float m = -1e30f;
#pragma unroll
    for (int ct = 0; ct < 16; ++ct) m = fmaxf(m, s[ct][r]);
    rm[r] = m;
  }
#pragma unroll
  for (int off = 1; off < 16; off <<= 1)
#pragma unroll
    for (int r = 0; r < 4; ++r) rm[r] = fmaxf(rm[r], __shfl_xor(rm[r], off, 64));
#pragma unroll
  for (int r = 0; r < 4; ++r) {
    float sum = 0.f;
#pragma unroll
    for (int ct = 0; ct < 16; ++ct) {
      float p = __expf(s[ct][r] - rm[r]);
      s[ct][r] = p;
      sum += p;
    }
    rs[r] = sum;
  }
#pragma unroll
  for (int off = 1; off < 16; off <<= 1)
#pragma unroll
    for (int r = 0; r < 4; ++r) rs[r] += __shfl_xor(rs[r], off, 64);
#pragma unroll
  for (int r = 0; r < 4; ++r) inv[r] = 1.0f / rs[r];

  // write P (bf16) to per-wave LDS region in [row][col] layout
#pragma unroll
  for (int ct = 0; ct < 16; ++ct)
#pragma unroll
    for (int r = 0; r < 4; ++r)
      pw[(quad * 4 + r) * PSTRIDE + ct * 16 + l16] = f2bf(s[ct][r]);

  // ---- PV memory chunks (cols 0..127) ----
  floatx4 o[4] = {};
#pragma unroll
  for (int ks = 0; ks < 4; ++ks) {
    short8 pa = *reinterpret_cast<const short8*>(pw + l16 * PSTRIDE + ks * 32 + quad * 8);
#pragma unroll
    for (int dt = 0; dt < 4; ++dt) {
      int c0 = ks * 4 + quad;
      int slot = (c0 & 8) | ((c0 & 7) ^ (l16 & 7));
      short8 vb = *reinterpret_cast<const short8*>(Vmem + (dt * 16 + l16) * 128 + slot * 8);
      o[dt] = __builtin_amdgcn_mfma_f32_16x16x32_bf16(pa, vb, o[dt], 0, 0, 0);
    }
  }
  // ---- PV window chunks: 3 of 4 reachable per wave ----
#pragma unroll
  for (int ks = 0; ks < 4; ++ks) {
    if (ks >= (w >> 1) && ks <= 2 + (w >> 1)) {
      short8 pa = *reinterpret_cast<const short8*>(pw + l16 * PSTRIDE + (4 + ks) * 32 + quad * 8);
#pragma unroll
      for (int dt = 0; dt < 4; ++dt) {
        int c0 = ks * 4 + quad;
        int slot = (c0 & 8) | ((c0 & 7) ^ (l16 & 7));
        short8 vb = *reinterpret_cast<const short8*>(Vwin + (dt * 16 + l16) * 128 + slot * 8);
        o[dt] = __builtin_amdgcn_mfma_f32_16x16x32_bf16(pa, vb, o[dt], 0, 0, 0);
      }
    }
  }

  // epilogue: normalize, gate, store bf16 row-major [b, t, c]
#pragma unroll
  for (int dt = 0; dt < 4; ++dt) {
    int c = h * 64 + dt * 16 + l16;
    float g = gate[c];
#pragma unroll
    for (int r = 0; r < 4; ++r) {
      int t = t0 + w * 16 + quad * 4 + r;
      float val = o[dt][r] * inv[r] * g;
      aout[((size_t)b * Tt + t) * Cc + c] = f2bf(val);
    }
  }
}

// ---------------- GEMM 2: out = aout @ proj_w^T + b, * loss_mask ----------------
// grid (3, 512), m97 structure, same as gemm_qkv.

__global__ __launch_bounds__(256) void gemm_proj(const unsigned short* __restrict__ ab,  // [65536][384]
                                                 const unsigned short* __restrict__ pwb, // [384][384]
                                                 const float* __restrict__ proj_b,
                                                 const float* __restrict__ loss_mask,    // [65536]
                                                 float* __restrict__ out)                // [65536][384]
{
  int tid = threadIdx.x;
  int w = tid >> 6, lane = tid & 63, quad = lane >> 4, l16 = lane & 15;
  int rowbase = blockIdx.y * 128;
  int colbase = blockIdx.x * 128;
  int rowofs = (w >> 1) * 64, colofs = (w & 1) * 64;

  __shared__ __align__(16) unsigned short Alds[128 * 32];
  __shared__ __align__(16) unsigned short Blds[128 * 32];

  int srow = lane >> 2;
  int skc = (lane & 3) * 8;

  floatx4 acc[4][4] = {};
  for (int ks = 0; ks < 12; ++ks) {
    int kk = ks * 32;
#pragma unroll
    for (int c = w; c < 8; c += 4) {
      gl2lds16(ab + (size_t)(rowbase + c * 16 + srow) * 384 + kk + skc,
               &Alds[c * 512 + lane * 8]);
      gl2lds16(pwb + (size_t)(colbase + c * 16 + srow) * 384 + kk + skc,
               &Blds[c * 512 + lane * 8]);
    }
    __syncthreads();

    short8 a[4], b[4];
#pragma unroll
    for (int rt = 0; rt < 4; ++rt)
      a[rt] = *reinterpret_cast<const short8*>(&Alds[(rowofs + rt * 16 + l16) * 32 + quad * 8]);
#pragma unroll
    for (int nt = 0; nt < 4; ++nt)
      b[nt] = *reinterpret_cast<const short8*>(&Blds[(colofs + nt * 16 + l16) * 32 + quad * 8]);
#pragma unroll
    for (int rt = 0; rt < 4; ++rt)
#pragma unroll
      for (int nt = 0; nt < 4; ++nt)
        acc[rt][nt] = __builtin_amdgcn_mfma_f32_16x16x32_bf16(a[rt], b[nt], acc[rt][nt], 0, 0, 0);
    __syncthreads();
  }

#pragma unroll
  for (int nt = 0; nt < 4; ++nt) {
    int col = colbase + colofs + nt * 16 + l16;
    float bias = proj_b[col];
#pragma unroll
    for (int rt = 0; rt < 4; ++rt) {
#pragma unroll
      for (int r = 0; r < 4; ++r) {
        int row = rowbase + rowofs + rt * 16 + quad * 4 + r;
        float val = (acc[rt][nt][r] + bias) * loss_mask[row];
        out[(size_t)row * 384 + col] = val;
      }
    }
  }
}

// ---------------- launcher ----------------

extern "C" void kernel_launch(void* const* d_in, const int* in_sizes, int n_in,
                              void* d_out, int out_size, void* d_ws, size_t ws_size,
                              hipStream_t stream) {
  const float* x = (const float*)d_in[0];
  const float* memory = (const float*)d_in[1];
  const float* loss_mask = (const float*)d_in[2];
  const float* qkv_w = (const float*)d_in[3];
  const float* qkv_b = (const float*)d_in[4];
  const float* proj_w = (const float*)d_in[5];
  const float* proj_b = (const float*)d_in[6];
  const float* gate = (const float*)d_in[7];
  float* out = (float*)d_out;

  char* ws = (char*)d_ws;
  // byte offsets (all 16B aligned). xb is reused as aout (dead after gemm_qkv).
  unsigned short* xb    = (unsigned short*)(ws + 0);            // 50,331,648 B
  unsigned short* qb    = (unsigned short*)(ws + 50331648);     // 50,331,648 B
  unsigned short* kb    = (unsigned short*)(ws + 100663296);    // 50,331,648 B
  unsigned short* vtb   = (unsigned short*)(ws + 150994944);    // 50,331,648 B
  unsigned short* wb    = (unsigned short*)(ws + 201326592);    //    884,736 B
  unsigned short* pwb   = (unsigned short*)(ws + 202211328);    //    294,912 B
  unsigned short* memk  = (unsigned short*)(ws + 202506240);    //     98,304 B
  unsigned short* memvt = (unsigned short*)(ws + 202604544);    //     98,304 B
  unsigned short* aout  = xb;

  cvt_x<<<dim3(24576), dim3(256), 0, stream>>>((const float4*)x, (ushort4*)xb);
  cvt_misc<<<dim3(1728), dim3(256), 0, stream>>>(qkv_w, proj_w, memory, wb, pwb, memk, memvt);
  gemm_qkv<<<dim3(9, 512), dim3(256), 0, stream>>>(xb, wb, qkv_b, qb, kb, vtb);
  attn<<<dim3(4, 6, 256), dim3(256), 0, stream>>>(qb, kb, vtb, memk, memvt, gate, aout);
  gemm_proj<<<dim3(3, 512), dim3(256), 0, stream>>>(aout, pwb, proj_b, loss_mask, out);
}